// Round 1
// 540.095 us; speedup vs baseline: 1.0037x; 1.0037x over previous
//
#include <hip/hip_runtime.h>
#include <math.h>

#define BB 4
#define TP 8192
#define TT 8193          // TP + 1
#define EE 4096
#define HH 32
#define HKV 8
#define DD 128
#define MM 256
#define GG 4             // H / HKV
#define NSEG 48          // H + 2*HKV row-segments of 128
#define ESPLIT 8         // E-split for qkv GEMV (512-col chunks)
#define TB 64            // t-rows per logits block
#define NT2 129          // ceil(8193/64)
#define TCH 256          // t-rows per wv chunk
#define WCH 33           // ceil(8193/256) value chunks per (b,kv)

#define CJL 0.0048957583420918762f     // sqrt(pi/2)/256
#define RSQRT_D 0.08838834764831845f   // 1/sqrt(128)
#define NEG_HUGE -3.402823466e38f

#define KSTR 136         // kt row stride in f16
#define SSTR 276         // sign row stride in f16 (552 B: conflict-free b16 writes)

typedef _Float16 f16x8 __attribute__((ext_vector_type(8)));
typedef _Float16 f16x4 __attribute__((ext_vector_type(4)));
typedef float f32x4 __attribute__((ext_vector_type(4)));

// ---- workspace layout (float offsets); qkvp/scorep die before logits and
// are overlaid by the logits buffer (stream-ordered, safe) ----
#define OFF_Q      0            // q_rope   B*H*D    = 16384
#define OFF_KN     16384        // k_new    B*HKV*D  = 4096
#define OFF_VN     20480        // v_new               4096
#define OFF_MASKF  24576        // 1-omask             4096
#define OFF_STATS  28672        // softmax row stats (mx, 1/sum) -> 256 fl (ex-qoval slot)
#define OFF_AO     29696        // attn out B*H*D    = 16384 (zeroed in rowstat)
#define OFF_INT    46080        // ints: pos (4096), oidx (256) -> 4352 floats
#define OFF_QSF    50432        // qs f16 padded [bk][16][256] -> 65536 fl reserved
#define OFF_SFRAG  115968       // S frags hi/lo (f16) -> 65536 fl reserved
#define OFF_QKVP   181504       // qkv partials [8][48][4][128] = 196608 fl
#define OFF_SCOREP 378112       // score partials [64][32][128] = 262144 fl
#define OFF_LOGITS 181504       // B*HKV*G*T = 1048704 fl  (overlays qkvp+scorep)

#define QKV_BLKS  (NSEG * ESPLIT)          // 384
#define SCORE_BLKS (BB * HKV * 64)         // 2048

// ============ K1: fused qkv-partial GEMV (all-b) + score + S-frag prep ======
__global__ __launch_bounds__(256) void k1_kernel(
    const float* __restrict__ hs, const float* __restrict__ pk,
    const float* __restrict__ Wq, const float* __restrict__ Wk,
    const float* __restrict__ Wv, const float* __restrict__ Sp,
    float* __restrict__ qkvp, float* __restrict__ scorep,
    _Float16* __restrict__ Sfhi, _Float16* __restrict__ Sflo)
{
  __shared__ float smem[3072];   // 12 KB, carved per branch
  int bid = blockIdx.x, tid = threadIdx.x;
  if (bid < QKV_BLKS) {
    // ---- qkv partial: (seg, c); 128 rows x 512-E-chunk x ALL 4 b ----
    int c = bid & 7;
    int seg = bid >> 3;
    const float* W;
    if (seg < HH)            W = Wq + (size_t)seg * DD * EE;
    else if (seg < HH + HKV) W = Wk + (size_t)(seg - HH) * DD * EE;
    else                     W = Wv + (size_t)(seg - HH - HKV) * DD * EE;
    float* hsl  = smem;          // [4][512]
    float* sred = smem + 2048;   // [2][4][128] -> 1024 fl
    for (int i = tid; i < 4 * 512; i += 256) {
      int b = i >> 9, col = i & 511;
      hsl[i] = hs[b * EE + c * 512 + col];
    }
    __syncthreads();
    int row = tid & 127, half = tid >> 7;
    const float* wr = W + (size_t)row * EE + c * 512 + half * 256;
    float4 acc[BB];
    #pragma unroll
    for (int b = 0; b < BB; ++b) acc[b] = make_float4(0.f, 0.f, 0.f, 0.f);
    for (int j = 0; j < 256; j += 4) {
      float4 w4 = *(const float4*)(wr + j);
      #pragma unroll
      for (int b = 0; b < BB; ++b) {
        float4 a4 = *(const float4*)&hsl[b * 512 + half * 256 + j];  // broadcast
        acc[b].x = fmaf(w4.x, a4.x, acc[b].x);
        acc[b].y = fmaf(w4.y, a4.y, acc[b].y);
        acc[b].z = fmaf(w4.z, a4.z, acc[b].z);
        acc[b].w = fmaf(w4.w, a4.w, acc[b].w);
      }
    }
    #pragma unroll
    for (int b = 0; b < BB; ++b)
      sred[(half * BB + b) * DD + row] = (acc[b].x + acc[b].y) + (acc[b].z + acc[b].w);
    __syncthreads();
    for (int i = tid; i < BB * DD; i += 256) {
      int b = i >> 7, d = i & 127;
      qkvp[(((size_t)c * NSEG + seg) * BB + b) * DD + d] =
          sred[b * DD + d] + sred[(BB + b) * DD + d];
    }
  } else if (bid < QKV_BLKS + SCORE_BLKS) {
    // ---- score partial: sum_t |K[t,d]| over a 128-t chunk, float4 ----
    int id = bid - QKV_BLKS;
    int chunk = id & 63, bk = id >> 6;
    const float* base = pk + (size_t)bk * TP * DD + (size_t)chunk * 128 * DD;
    int tsub = tid >> 5, d4 = (tid & 31) * 4;
    float4 a = make_float4(0.f, 0.f, 0.f, 0.f);
    for (int t = tsub; t < 128; t += 8) {
      float4 v = *(const float4*)(base + (size_t)t * DD + d4);
      a.x += fabsf(v.x); a.y += fabsf(v.y); a.z += fabsf(v.z); a.w += fabsf(v.w);
    }
    *(float4*)&smem[tsub * DD + d4] = a;
    __syncthreads();
    if (tid < DD) {
      float s = 0.f;
      #pragma unroll
      for (int u = 0; u < 8; ++u) s += smem[u * DD + tid];
      scorep[((size_t)chunk * BB * HKV + bk) * DD + tid] = s;
    }
  } else {
    // ---- sprep: S -> f16 hi/lo fragments in MFMA-lane-swizzled layout ----
    int id = bid - QKV_BLKS - SCORE_BLKS;   // 0..15 = mt*4+ks
    int mt = id >> 2, ks = id & 3;
    int w = tid >> 6, q = (tid >> 4) & 3, l15 = tid & 15;
    f16x8 hi, lo;
    #pragma unroll
    for (int j = 0; j < 8; ++j) {
      float s = Sp[(ks * 32 + q * 8 + j) * MM + w * 64 + mt * 16 + l15];
      _Float16 h = (_Float16)s;
      hi[j] = h;
      lo[j] = (_Float16)(s - (float)h);
    }
    *(f16x8*)&Sfhi[(size_t)(id * 256 + tid) * 8] = hi;
    *(f16x8*)&Sflo[(size_t)(id * 256 + tid) * 8] = lo;
  }
}

// ============ K2: qkv finalize — sum 8 partials + RoPE ============
__global__ __launch_bounds__(256) void qkv_finalize_kernel(
    const float* __restrict__ qkvp, const float* __restrict__ cosb,
    const float* __restrict__ sinb, float* __restrict__ q_out,
    float* __restrict__ k_out, float* __restrict__ v_out)
{
  int gid = blockIdx.x * 256 + threadIdx.x;   // < 24576
  int b = gid / 6144;
  int r = gid - b * 6144;
  int seg = r >> 7, d = r & 127;
  float sum = 0.f;
  #pragma unroll
  for (int c = 0; c < ESPLIT; ++c)
    sum += qkvp[(((size_t)c * NSEG + seg) * BB + b) * DD + d];
  if (seg >= HH + HKV) {
    v_out[((size_t)b * HKV + (seg - HH - HKV)) * DD + d] = sum;
  } else {
    float part = 0.f;
    int dp = d ^ 64;
    #pragma unroll
    for (int c = 0; c < ESPLIT; ++c)
      part += qkvp[(((size_t)c * NSEG + seg) * BB + b) * DD + dp];
    float cc = cosb[b * DD + d], ss = sinb[b * DD + d];
    float other = (d < 64) ? -part : part;
    float rv = fmaf(sum, cc, other * ss);
    if (seg < HH) q_out[((size_t)b * HH + seg) * DD + d] = rv;
    else          k_out[((size_t)b * HKV + (seg - HH)) * DD + d] = rv;
  }
}

// ============ K3: top-8 outlier channels ============
__global__ __launch_bounds__(128) void topk_kernel(
    const float* __restrict__ scorep, const float* __restrict__ k_new,
    float* __restrict__ maskf, int* __restrict__ pos, int* __restrict__ oidx)
{
  int bk = blockIdx.x;
  int tid = threadIdx.x;
  __shared__ float sv[DD];
  __shared__ int si[DD];
  float cur = 0.f;
  for (int c = 0; c < 64; ++c)
    cur += scorep[((size_t)c * BB * HKV + bk) * DD + tid];
  cur += fabsf(k_new[bk * DD + tid]);
  maskf[bk * DD + tid] = 1.f;
  pos[bk * DD + tid] = -1;
  for (int o = 0; o < 8; ++o) {
    sv[tid] = cur; si[tid] = tid;
    __syncthreads();
    for (int st = 64; st > 0; st >>= 1) {
      if (tid < st) {
        float a = sv[tid], c2 = sv[tid + st];
        int ia = si[tid], ic = si[tid + st];
        if (c2 > a || (c2 == a && ic < ia)) { sv[tid] = c2; si[tid] = ic; }
      }
      __syncthreads();
    }
    int mi = si[0];
    __syncthreads();
    if (tid == 0) oidx[bk * 8 + o] = mi;
    if (tid == mi) { pos[bk * DD + tid] = o; maskf[bk * DD + tid] = 0.f; cur = NEG_HUGE; }
  }
}

// ============ K4: qs = q_in @ S (f16 padded) ============
__global__ __launch_bounds__(256) void qs_kernel(
    const float* __restrict__ q_rope, const float* __restrict__ maskf,
    const float* __restrict__ Sp, _Float16* __restrict__ qsfT)
{
  int bkg = blockIdx.x;
  int bk = bkg >> 2, g = bkg & 3;
  int b = bk >> 3, kv = bk & 7;
  __shared__ float qin[DD];
  if (threadIdx.x < DD) {
    float qv = q_rope[((size_t)b * HH + kv * GG + g) * DD + threadIdx.x];
    qin[threadIdx.x] = qv * maskf[bk * DD + threadIdx.x];
  }
  __syncthreads();
  int m = threadIdx.x;
  float acc = 0.f;
  for (int d = 0; d < DD; ++d)
    acc = fmaf(qin[d], Sp[d * MM + m], acc);
  qsfT[((size_t)bk * 16 + g) * MM + m] = (_Float16)acc;
  if (g == 0) {
    #pragma unroll
    for (int n = 4; n < 16; ++n)
      qsfT[((size_t)bk * 16 + n) * MM + m] = (_Float16)0.f;
  }
}

// ============ K5: logits via f16 hi/lo MFMA, S streamed per-ks ============
// Staging is branch-free and burst-issued: all global loads of a block are
// emitted in one basic block (single latency exposure). The exact-outlier
// term ex[g][t] = sum_d q_out[g,d]*K[t,d] is computed in-register during
// staging (q_out is zero off outlier dims -> identical math to the old
// pos[]/koutl gather, no divergence, no indirection chain).
__global__ __launch_bounds__(256) void logits_kernel(
    const float* __restrict__ pk, const float* __restrict__ k_new,
    const _Float16* __restrict__ Sfhi, const _Float16* __restrict__ Sflo,
    const _Float16* __restrict__ qsfT, const float* __restrict__ q_rope,
    const float* __restrict__ maskf, const float* __restrict__ amask,
    float* __restrict__ logits)
{
  __shared__ union {
    struct { _Float16 hi[TB * KSTR]; _Float16 lo[TB * KSTR]; } k;  // 34816 B
    _Float16 ssg[TB * SSTR];                                       // 35328 B
  } u;
  __shared__ float norm2[TB];
  __shared__ float exv[TB][GG];

  int bk = blockIdx.x / NT2;
  int tile = blockIdx.x % NT2;
  int b = bk >> 3, kv = bk & 7;
  int t0 = tile * TB;
  int tid = threadIdx.x;
  int l15 = tid & 15;
  int q   = (tid >> 4) & 3;
  int w   = tid >> 6;
  int mb  = w * 64;
  int d4  = (tid & 31) * 4;
  int tsub = tid >> 5;

  // ---- phase 1: burst-issue every load this block needs ----
  float4 mk4 = *(const float4*)&maskf[bk * DD + d4];
  float4 qo4[GG];
  #pragma unroll
  for (int g = 0; g < GG; ++g) {
    float4 qr = *(const float4*)&q_rope[((size_t)b * HH + kv * GG + g) * DD + d4];
    qo4[g].x = qr.x * (1.f - mk4.x);
    qo4[g].y = qr.y * (1.f - mk4.y);
    qo4[g].z = qr.z * (1.f - mk4.z);
    qo4[g].w = qr.w * (1.f - mk4.w);
  }
  float4 kvr[8];
  #pragma unroll
  for (int iter = 0; iter < 8; ++iter) {
    int tg = t0 + iter * 8 + tsub;
    const float* row = (tg < TP) ? pk + ((size_t)bk * TP + tg) * DD
                                 : k_new + (size_t)bk * DD;   // cndmask, no branch
    kvr[iter] = *(const float4*)(row + d4);
  }

  // ---- phase 2: mask, exact term, norms, hi/lo cvt, LDS stage ----
  #pragma unroll
  for (int iter = 0; iter < 8; ++iter) {
    int tl = iter * 8 + tsub;
    int tg = t0 + tl;
    float inb = (tg <= TP) ? 1.f : 0.f;
    float kx = kvr[iter].x * inb, ky = kvr[iter].y * inb,
          kz = kvr[iter].z * inb, kw = kvr[iter].w * inb;
    float exg[GG];
    #pragma unroll
    for (int g = 0; g < GG; ++g)
      exg[g] = (qo4[g].x * kx + qo4[g].y * ky) + (qo4[g].z * kz + qo4[g].w * kw);
    float v[4] = {kx * mk4.x, ky * mk4.y, kz * mk4.z, kw * mk4.w};
    float nrm = 0.f;
    f16x4 hi4, lo4;
    #pragma unroll
    for (int j = 0; j < 4; ++j) {
      nrm = fmaf(v[j], v[j], nrm);
      _Float16 h = (_Float16)v[j];
      hi4[j] = h;
      lo4[j] = (_Float16)(v[j] - (float)h);
    }
    *(f16x4*)&u.k.hi[tl * KSTR + d4] = hi4;
    *(f16x4*)&u.k.lo[tl * KSTR + d4] = lo4;
    #pragma unroll
    for (int off = 16; off > 0; off >>= 1) {   // stays within the 32-lane row group
      nrm += __shfl_xor(nrm, off);
      #pragma unroll
      for (int g = 0; g < GG; ++g) exg[g] += __shfl_xor(exg[g], off);
    }
    if ((tid & 31) == 0) {
      norm2[tl] = nrm;
      #pragma unroll
      for (int g = 0; g < GG; ++g) exv[tl][g] = exg[g];
    }
  }
  __syncthreads();

  // ---- MFMA loop: ks-chunked S streaming (8 frags resident at a time) ----
  f32x4 acc[4][4];
  #pragma unroll
  for (int ts = 0; ts < 4; ++ts)
    #pragma unroll
    for (int mt = 0; mt < 4; ++mt)
      acc[ts][mt] = (f32x4){0.f, 0.f, 0.f, 0.f};

  const f16x8* SH = (const f16x8*)Sfhi;
  const f16x8* SL = (const f16x8*)Sflo;
  #pragma unroll
  for (int ks = 0; ks < 4; ++ks) {
    f16x8 sh[4], sl[4], ah[4], al[4];
    #pragma unroll
    for (int mt = 0; mt < 4; ++mt) {
      sh[mt] = SH[(size_t)(mt * 4 + ks) * 256 + tid];
      sl[mt] = SL[(size_t)(mt * 4 + ks) * 256 + tid];
    }
    #pragma unroll
    for (int ts = 0; ts < 4; ++ts) {
      ah[ts] = *(const f16x8*)&u.k.hi[(ts * 16 + l15) * KSTR + ks * 32 + q * 8];
      al[ts] = *(const f16x8*)&u.k.lo[(ts * 16 + l15) * KSTR + ks * 32 + q * 8];
    }
    #pragma unroll
    for (int ts = 0; ts < 4; ++ts)
      #pragma unroll
      for (int mt = 0; mt < 4; ++mt) {
        acc[ts][mt] = __builtin_amdgcn_mfma_f32_16x16x32_f16(ah[ts], sh[mt], acc[ts][mt], 0, 0, 0);
        acc[ts][mt] = __builtin_amdgcn_mfma_f32_16x16x32_f16(al[ts], sh[mt], acc[ts][mt], 0, 0, 0);
        acc[ts][mt] = __builtin_amdgcn_mfma_f32_16x16x32_f16(ah[ts], sl[mt], acc[ts][mt], 0, 0, 0);
      }
  }
  __syncthreads();   // done reading kt; LDS reused for sign matrix

  // ---- write sign matrix (C-layout -> [t][m] f16) ----
  #pragma unroll
  for (int ts = 0; ts < 4; ++ts)
    #pragma unroll
    for (int mt = 0; mt < 4; ++mt)
      #pragma unroll
      for (int r = 0; r < 4; ++r) {
        int tl = ts * 16 + q * 4 + r;
        int mm = mb + mt * 16 + l15;
        u.ssg[tl * SSTR + mm] = acc[ts][mt][r] >= 0.f ? (_Float16)1.f : (_Float16)-1.f;
      }
  __syncthreads();

  // ---- est = sign @ qs^T via MFMA; wave w handles t in [16w, 16w+16) ----
  f32x4 eacc = (f32x4){0.f, 0.f, 0.f, 0.f};
  const _Float16* qrow = qsfT + ((size_t)bk * 16 + l15) * MM;
  #pragma unroll
  for (int ks = 0; ks < 8; ++ks) {
    f16x8 as = *(const f16x8*)&u.ssg[(16 * w + l15) * SSTR + ks * 32 + q * 8];
    f16x8 bq = *(const f16x8*)&qrow[ks * 32 + q * 8];
    eacc = __builtin_amdgcn_mfma_f32_16x16x32_f16(as, bq, eacc, 0, 0, 0);
  }

  // ---- assemble logits: lanes with l15 < 4 hold est for g = l15 ----
  if (l15 < 4) {
    int g = l15;
    #pragma unroll
    for (int r = 0; r < 4; ++r) {
      int tl = 16 * w + q * 4 + r;
      int tg = t0 + tl;
      if (tg < TT) {
        float logit = fmaf(eacc[r] * CJL, sqrtf(norm2[tl]), exv[tl][g]) * RSQRT_D;
        logit += (1.f - amask[b * TT + tg]) * NEG_HUGE;
        logits[((size_t)(bk * GG + g)) * TT + tg] = logit;
      }
    }
  }
}

// ============ K6: per-row softmax stats (mx, 1/sum) + zero attn_o ============
// Weights are never materialized; wv applies exp on the fly.
__global__ __launch_bounds__(256) void rowstat_kernel(
    const float* __restrict__ logits, float* __restrict__ stats,
    float* __restrict__ attn_o)
{
  int row = blockIdx.x;
  const float* L = logits + (size_t)row * TT;
  int tid = threadIdx.x;
  int lane = tid & 63, wid = tid >> 6;
  __shared__ float red[8];
  if (tid < 128) attn_o[(size_t)row * DD + tid] = 0.f;
  float mx = NEG_HUGE;
  for (int i = tid; i < TT; i += 256) mx = fmaxf(mx, L[i]);
  #pragma unroll
  for (int off = 32; off > 0; off >>= 1) mx = fmaxf(mx, __shfl_xor(mx, off));
  if (lane == 0) red[wid] = mx;
  __syncthreads();
  if (tid == 0) red[4] = fmaxf(fmaxf(red[0], red[1]), fmaxf(red[2], red[3]));
  __syncthreads();
  mx = red[4];
  float sum = 0.f;
  for (int i = tid; i < TT; i += 256) sum += __expf(L[i] - mx);
  #pragma unroll
  for (int off = 32; off > 0; off >>= 1) sum += __shfl_xor(sum, off);
  if (lane == 0) red[wid] = sum;
  __syncthreads();
  if (tid == 0) {
    float s = (red[0] + red[1]) + (red[2] + red[3]);
    stats[row * 2]     = mx;
    stats[row * 2 + 1] = 1.f / s;
  }
}

// ============ K7: out_head = softmax(logits) @ V, exp fused into staging ======
__global__ __launch_bounds__(256) void wv_kernel(
    const float* __restrict__ pv, const float* __restrict__ v_new,
    const float* __restrict__ logits, const float* __restrict__ stats,
    float* __restrict__ attn_out)
{
  __shared__ float wl[GG * TCH];     // 4 KB
  __shared__ float red[8][GG][DD];   // 16 KB
  int bk = blockIdx.x / WCH;
  int chunk = blockIdx.x % WCH;
  int b = bk >> 3, kv = bk & 7;
  int t0 = chunk * TCH;
  const float* wbase = logits + (size_t)bk * GG * TT;
  for (int i = threadIdx.x; i < GG * TCH; i += 256) {
    int g = i >> 8, tloc = i & (TCH - 1);
    int t = t0 + tloc;
    float mxg  = stats[(bk * GG + g) * 2];
    float invg = stats[(bk * GG + g) * 2 + 1];
    wl[i] = (t < TT) ? __expf(wbase[g * TT + t] - mxg) * invg : 0.f;
  }
  __syncthreads();
  int tsub = threadIdx.x >> 5;
  int d4 = (threadIdx.x & 31) * 4;
  int tend = (t0 + TCH < TT) ? t0 + TCH : TT;
  float4 acc[GG];
  #pragma unroll
  for (int g = 0; g < GG; ++g) acc[g] = make_float4(0.f, 0.f, 0.f, 0.f);
  for (int t = t0 + tsub; t < tend; t += 8) {
    float4 v = (t < TP) ? *(const float4*)(pv + ((size_t)bk * TP + t) * DD + d4)
                        : *(const float4*)(v_new + (size_t)bk * DD + d4);
    #pragma unroll
    for (int g = 0; g < GG; ++g) {
      float wv = wl[g * TCH + (t - t0)];   // broadcast
      acc[g].x = fmaf(wv, v.x, acc[g].x);
      acc[g].y = fmaf(wv, v.y, acc[g].y);
      acc[g].z = fmaf(wv, v.z, acc[g].z);
      acc[g].w = fmaf(wv, v.w, acc[g].w);
    }
  }
  #pragma unroll
  for (int g = 0; g < GG; ++g) *(float4*)&red[tsub][g][d4] = acc[g];
  __syncthreads();
  if (threadIdx.x < DD) {
    int d = threadIdx.x;
    #pragma unroll
    for (int g = 0; g < GG; ++g) {
      float s = 0.f;
      #pragma unroll
      for (int ts = 0; ts < 8; ++ts) s += red[ts][g][d];
      atomicAdd(&attn_out[((size_t)b * HH + kv * GG + g) * DD + d], s);
    }
  }
}

// ============ K8: out = attn_out @ Wo^T, Wo read once (all 4 b) ============
// grid 256: each block = 16 e-rows x all b. al padded [16][260] per b.
__global__ __launch_bounds__(256) void outproj_kernel(
    const float* __restrict__ attn_out, const float* __restrict__ Wo,
    float* __restrict__ out)
{
  __shared__ float al[BB][16][260];   // 66560 B, pad breaks stride-256 conflicts
  int seg = blockIdx.x;
  int tid = threadIdx.x;
  for (int i = tid; i < BB * EE; i += 256) {
    int b = i >> 12, col = i & 4095;
    al[b][col >> 8][col & 255] = attn_out[(size_t)b * EE + col];
  }
  __syncthreads();
  int rloc = tid >> 4, sub = tid & 15;
  int e = seg * 16 + rloc;
  const float* wr = Wo + (size_t)e * EE + sub * 256;
  float acc[BB] = {0.f, 0.f, 0.f, 0.f};
  for (int j = 0; j < 256; j += 4) {
    float4 w4 = *(const float4*)(wr + j);
    #pragma unroll
    for (int b = 0; b < BB; ++b) {
      float4 a4 = *(const float4*)&al[b][sub][j];
      acc[b] = fmaf(w4.x, a4.x, acc[b]);
      acc[b] = fmaf(w4.y, a4.y, acc[b]);
      acc[b] = fmaf(w4.z, a4.z, acc[b]);
      acc[b] = fmaf(w4.w, a4.w, acc[b]);
    }
  }
  #pragma unroll
  for (int b = 0; b < BB; ++b) {
    acc[b] += __shfl_xor(acc[b], 1);
    acc[b] += __shfl_xor(acc[b], 2);
    acc[b] += __shfl_xor(acc[b], 4);
    acc[b] += __shfl_xor(acc[b], 8);
  }
  if (sub == 0) {
    #pragma unroll
    for (int b = 0; b < BB; ++b)
      out[(size_t)b * EE + e] = acc[b];
  }
}

// ===================== launcher =====================
extern "C" void kernel_launch(void* const* d_in, const int* in_sizes, int n_in,
                              void* d_out, int out_size, void* d_ws, size_t ws_size,
                              hipStream_t stream)
{
  const float* hs    = (const float*)d_in[0];
  const float* cosb  = (const float*)d_in[1];
  const float* sinb  = (const float*)d_in[2];
  const float* pk    = (const float*)d_in[3];
  const float* pv    = (const float*)d_in[4];
  const float* amask = (const float*)d_in[5];
  const float* Wq    = (const float*)d_in[6];
  const float* Wk    = (const float*)d_in[7];
  const float* Wv    = (const float*)d_in[8];
  const float* Wo    = (const float*)d_in[9];
  const float* Sp    = (const float*)d_in[10];
  float* out = (float*)d_out;
  float* ws = (float*)d_ws;

  float* q_rope = ws + OFF_Q;
  float* k_new  = ws + OFF_KN;
  float* v_new  = ws + OFF_VN;
  float* maskf  = ws + OFF_MASKF;
  float* stats  = ws + OFF_STATS;
  float* attn_o = ws + OFF_AO;
  int*   pos    = (int*)(ws + OFF_INT);
  int*   oidx   = pos + BB * HKV * DD;
  _Float16* qsfT = (_Float16*)(ws + OFF_QSF);
  _Float16* Sfhi = (_Float16*)(ws + OFF_SFRAG);
  _Float16* Sflo = Sfhi + 65536;
  float* qkvp   = ws + OFF_QKVP;
  float* scorep = ws + OFF_SCOREP;
  float* logits = ws + OFF_LOGITS;

  int k1_grid = QKV_BLKS + SCORE_BLKS + 16;   // 2448
  k1_kernel<<<k1_grid, 256, 0, stream>>>(hs, pk, Wq, Wk, Wv, Sp,
                                         qkvp, scorep, Sfhi, Sflo);
  qkv_finalize_kernel<<<96, 256, 0, stream>>>(qkvp, cosb, sinb,
                                              q_rope, k_new, v_new);
  topk_kernel<<<BB * HKV, 128, 0, stream>>>(scorep, k_new, maskf, pos, oidx);
  qs_kernel<<<BB * HKV * GG, 256, 0, stream>>>(q_rope, maskf, Sp, qsfT);
  logits_kernel<<<BB * HKV * NT2, 256, 0, stream>>>(pk, k_new, Sfhi, Sflo, qsfT,
                                                    q_rope, maskf, amask, logits);
  rowstat_kernel<<<BB * HKV * GG, 256, 0, stream>>>(logits, stats, attn_o);
  wv_kernel<<<BB * HKV * WCH, 256, 0, stream>>>(pv, v_new, logits, stats, attn_o);
  outproj_kernel<<<256, 256, 0, stream>>>(attn_o, Wo, out);
}

// Round 4
// 505.259 us; speedup vs baseline: 1.0729x; 1.0689x over previous
//
#include <hip/hip_runtime.h>
#include <math.h>

#define BB 4
#define TP 8192
#define TT 8193          // TP + 1
#define EE 4096
#define HH 32
#define HKV 8
#define DD 128
#define MM 256
#define GG 4             // H / HKV
#define NSEG 48          // H + 2*HKV row-segments of 128
#define ESPLIT 8         // E-split for qkv GEMV (512-col chunks)
#define TB 64            // t-rows per logits block
#define NT2 129          // ceil(8193/64)
#define TCH 256          // t-rows per wv chunk
#define WCH 33           // ceil(8193/256) value chunks per (b,kv)

#define CJL 0.0048957583420918762f     // sqrt(pi/2)/256
#define RSQRT_D 0.08838834764831845f   // 1/sqrt(128)
#define NEG_HUGE -3.402823466e38f

#define KSTR 136         // kt row stride in f16
#define SSTR 276         // sign row stride in f16 (552 B: conflict-free b16 writes)

typedef _Float16 f16x8 __attribute__((ext_vector_type(8)));
typedef _Float16 f16x4 __attribute__((ext_vector_type(4)));
typedef _Float16 f16x2 __attribute__((ext_vector_type(2)));
typedef float f32x4 __attribute__((ext_vector_type(4)));

// ---- workspace layout (float offsets); qkvp/scorep die before logits and
// are overlaid by the logits buffer (stream-ordered, safe) ----
#define OFF_Q      0            // q_rope   B*H*D    = 16384
#define OFF_KN     16384        // k_new    B*HKV*D  = 4096
#define OFF_VN     20480        // v_new               4096
#define OFF_MASKF  24576        // 1-omask             4096
#define OFF_STATS  28672        // softmax row stats (mx, 1/sum)
#define OFF_AO     29696        // attn out B*H*D    = 16384 (zeroed in rowstat)
#define OFF_MASKH  46080        // f16 mask table, 32*128 f16 = 2048 fl (ex-pos slot)
#define OFF_QSF    50432        // qs f16 padded [bk][16][256] -> 65536 fl
#define OFF_SFRAG  115968       // S frags hi/lo (f16) -> 65536 fl
#define OFF_QKVP   181504       // qkv partials [8][48][4][128] = 196608 fl
#define OFF_SCOREP 378112       // score partials [64][32][128] = 262144 fl
#define OFF_LOGITS 181504       // B*HKV*G*T = 1048704 fl  (overlays qkvp+scorep)
#define OFF_QOFH   1230208      // q_out hi frags [bk][4][64] f16x8 = 32768 fl
#define OFF_QOFL   1262976      // q_out lo frags                  = 32768 fl

#define QKV_BLKS  (NSEG * ESPLIT)          // 384
#define SCORE_BLKS (BB * HKV * 64)         // 2048

// ============ K1: fused qkv-partial GEMV (all-b) + score + S-frag prep ======
__global__ __launch_bounds__(256) void k1_kernel(
    const float* __restrict__ hs, const float* __restrict__ pk,
    const float* __restrict__ Wq, const float* __restrict__ Wk,
    const float* __restrict__ Wv, const float* __restrict__ Sp,
    float* __restrict__ qkvp, float* __restrict__ scorep,
    _Float16* __restrict__ Sfhi, _Float16* __restrict__ Sflo)
{
  __shared__ float smem[3072];   // 12 KB, carved per branch
  int bid = blockIdx.x, tid = threadIdx.x;
  if (bid < QKV_BLKS) {
    // ---- qkv partial: (seg, c); 128 rows x 512-E-chunk x ALL 4 b ----
    int c = bid & 7;
    int seg = bid >> 3;
    const float* W;
    if (seg < HH)            W = Wq + (size_t)seg * DD * EE;
    else if (seg < HH + HKV) W = Wk + (size_t)(seg - HH) * DD * EE;
    else                     W = Wv + (size_t)(seg - HH - HKV) * DD * EE;
    float* hsl  = smem;          // [4][512]
    float* sred = smem + 2048;   // [2][4][128] -> 1024 fl
    for (int i = tid; i < 4 * 512; i += 256) {
      int b = i >> 9, col = i & 511;
      hsl[i] = hs[b * EE + c * 512 + col];
    }
    __syncthreads();
    int row = tid & 127, half = tid >> 7;
    const float* wr = W + (size_t)row * EE + c * 512 + half * 256;
    float4 acc[BB];
    #pragma unroll
    for (int b = 0; b < BB; ++b) acc[b] = make_float4(0.f, 0.f, 0.f, 0.f);
    for (int j = 0; j < 256; j += 4) {
      float4 w4 = *(const float4*)(wr + j);
      #pragma unroll
      for (int b = 0; b < BB; ++b) {
        float4 a4 = *(const float4*)&hsl[b * 512 + half * 256 + j];  // broadcast
        acc[b].x = fmaf(w4.x, a4.x, acc[b].x);
        acc[b].y = fmaf(w4.y, a4.y, acc[b].y);
        acc[b].z = fmaf(w4.z, a4.z, acc[b].z);
        acc[b].w = fmaf(w4.w, a4.w, acc[b].w);
      }
    }
    #pragma unroll
    for (int b = 0; b < BB; ++b)
      sred[(half * BB + b) * DD + row] = (acc[b].x + acc[b].y) + (acc[b].z + acc[b].w);
    __syncthreads();
    for (int i = tid; i < BB * DD; i += 256) {
      int b = i >> 7, d = i & 127;
      qkvp[(((size_t)c * NSEG + seg) * BB + b) * DD + d] =
          sred[b * DD + d] + sred[(BB + b) * DD + d];
    }
  } else if (bid < QKV_BLKS + SCORE_BLKS) {
    // ---- score partial: sum_t |K[t,d]| over a 128-t chunk, float4 ----
    int id = bid - QKV_BLKS;
    int chunk = id & 63, bk = id >> 6;
    const float* base = pk + (size_t)bk * TP * DD + (size_t)chunk * 128 * DD;
    int tsub = tid >> 5, d4 = (tid & 31) * 4;
    float4 a = make_float4(0.f, 0.f, 0.f, 0.f);
    for (int t = tsub; t < 128; t += 8) {
      float4 v = *(const float4*)(base + (size_t)t * DD + d4);
      a.x += fabsf(v.x); a.y += fabsf(v.y); a.z += fabsf(v.z); a.w += fabsf(v.w);
    }
    *(float4*)&smem[tsub * DD + d4] = a;
    __syncthreads();
    if (tid < DD) {
      float s = 0.f;
      #pragma unroll
      for (int u = 0; u < 8; ++u) s += smem[u * DD + tid];
      scorep[((size_t)chunk * BB * HKV + bk) * DD + tid] = s;
    }
  } else {
    // ---- sprep: S -> f16 hi/lo fragments in MFMA-lane-swizzled layout ----
    int id = bid - QKV_BLKS - SCORE_BLKS;   // 0..15 = mt*4+ks
    int mt = id >> 2, ks = id & 3;
    int w = tid >> 6, q = (tid >> 4) & 3, l15 = tid & 15;
    f16x8 hi, lo;
    #pragma unroll
    for (int j = 0; j < 8; ++j) {
      float s = Sp[(ks * 32 + q * 8 + j) * MM + w * 64 + mt * 16 + l15];
      _Float16 h = (_Float16)s;
      hi[j] = h;
      lo[j] = (_Float16)(s - (float)h);
    }
    *(f16x8*)&Sfhi[(size_t)(id * 256 + tid) * 8] = hi;
    *(f16x8*)&Sflo[(size_t)(id * 256 + tid) * 8] = lo;
  }
}

// ============ K2: qkv finalize — sum 8 partials + RoPE ============
__global__ __launch_bounds__(256) void qkv_finalize_kernel(
    const float* __restrict__ qkvp, const float* __restrict__ cosb,
    const float* __restrict__ sinb, float* __restrict__ q_out,
    float* __restrict__ k_out, float* __restrict__ v_out)
{
  int gid = blockIdx.x * 256 + threadIdx.x;   // < 24576
  int b = gid / 6144;
  int r = gid - b * 6144;
  int seg = r >> 7, d = r & 127;
  float sum = 0.f;
  #pragma unroll
  for (int c = 0; c < ESPLIT; ++c)
    sum += qkvp[(((size_t)c * NSEG + seg) * BB + b) * DD + d];
  if (seg >= HH + HKV) {
    v_out[((size_t)b * HKV + (seg - HH - HKV)) * DD + d] = sum;
  } else {
    float part = 0.f;
    int dp = d ^ 64;
    #pragma unroll
    for (int c = 0; c < ESPLIT; ++c)
      part += qkvp[(((size_t)c * NSEG + seg) * BB + b) * DD + dp];
    float cc = cosb[b * DD + d], ss = sinb[b * DD + d];
    float other = (d < 64) ? -part : part;
    float rv = fmaf(sum, cc, other * ss);
    if (seg < HH) q_out[((size_t)b * HH + seg) * DD + d] = rv;
    else          k_out[((size_t)b * HKV + (seg - HH)) * DD + d] = rv;
  }
}

// ============ K3: top-8 outlier channels -> maskf (f32) + maskh (f16) ======
__global__ __launch_bounds__(128) void topk_kernel(
    const float* __restrict__ scorep, const float* __restrict__ k_new,
    float* __restrict__ maskf, _Float16* __restrict__ maskh)
{
  int bk = blockIdx.x;
  int tid = threadIdx.x;
  __shared__ float sv[DD];
  __shared__ int si[DD];
  float cur = 0.f;
  for (int c = 0; c < 64; ++c)
    cur += scorep[((size_t)c * BB * HKV + bk) * DD + tid];
  cur += fabsf(k_new[bk * DD + tid]);
  float mf = 1.f;
  for (int o = 0; o < 8; ++o) {
    sv[tid] = cur; si[tid] = tid;
    __syncthreads();
    for (int st = 64; st > 0; st >>= 1) {
      if (tid < st) {
        float a = sv[tid], c2 = sv[tid + st];
        int ia = si[tid], ic = si[tid + st];
        if (c2 > a || (c2 == a && ic < ia)) { sv[tid] = c2; si[tid] = ic; }
      }
      __syncthreads();
    }
    int mi = si[0];
    __syncthreads();
    if (tid == mi) { mf = 0.f; cur = NEG_HUGE; }
  }
  maskf[bk * DD + tid] = mf;
  maskh[bk * DD + tid] = (_Float16)mf;
}

// ============ K4: qs = q_in @ S (f16 padded) + q_out hi/lo B-frags ============
__global__ __launch_bounds__(256) void qs_kernel(
    const float* __restrict__ q_rope, const float* __restrict__ maskf,
    const float* __restrict__ Sp, _Float16* __restrict__ qsfT,
    _Float16* __restrict__ qofh, _Float16* __restrict__ qofl)
{
  int bkg = blockIdx.x;
  int bk = bkg >> 2, g = bkg & 3;
  int b = bk >> 3, kv = bk & 7;
  __shared__ float qin[DD];
  if (threadIdx.x < DD) {
    float qv = q_rope[((size_t)b * HH + kv * GG + g) * DD + threadIdx.x];
    qin[threadIdx.x] = qv * maskf[bk * DD + threadIdx.x];
  }
  __syncthreads();
  int m = threadIdx.x;
  float acc = 0.f;
  for (int d = 0; d < DD; ++d)
    acc = fmaf(qin[d], Sp[d * MM + m], acc);
  qsfT[((size_t)bk * 16 + g) * MM + m] = (_Float16)acc;
  if (g == 0) {
    #pragma unroll
    for (int n = 4; n < 16; ++n)
      qsfT[((size_t)bk * 16 + n) * MM + m] = (_Float16)0.f;
  }
  if (g == 1) {
    // build q_out B-frags for the ex-MFMA: per ks, lane holds column l15
    // (=g if <4, else 0), elements j -> d = ks*32 + q*8 + j
    int ks = threadIdx.x >> 6, lane = threadIdx.x & 63;
    int qq = (lane >> 4) & 3, l15 = lane & 15;
    f16x8 qh, ql;
    #pragma unroll
    for (int j = 0; j < 8; ++j) {
      int d = ks * 32 + qq * 8 + j;
      float val = 0.f;
      if (l15 < 4)
        val = q_rope[((size_t)b * HH + kv * GG + l15) * DD + d] *
              (1.f - maskf[bk * DD + d]);
      _Float16 h = (_Float16)val;
      qh[j] = h;
      ql[j] = (_Float16)(val - (float)h);
    }
    *(f16x8*)&qofh[((size_t)(bk * 4 + ks) * 64 + lane) * 8] = qh;
    *(f16x8*)&qofl[((size_t)(bk * 4 + ks) * 64 + lane) * 8] = ql;
  }
}

// ---- norm^2 accumulation step: pair P (literal) of a f16x8 hi/lo frag ----
#if __has_builtin(__builtin_amdgcn_fdot2)
#define NRM_STEP(P, AH, AL)                                                   \
  {                                                                           \
    f16x2 ph = {(AH)[2 * P], (AH)[2 * P + 1]};                                \
    f16x2 pl = {(AL)[2 * P], (AL)[2 * P + 1]};                                \
    nhh = __builtin_amdgcn_fdot2(ph, ph, nhh, false);                         \
    nhl = __builtin_amdgcn_fdot2(ph, pl, nhl, false);                         \
  }
#else
#define NRM_STEP(P, AH, AL)                                                   \
  {                                                                           \
    float h0 = (float)(AH)[2 * P], h1 = (float)(AH)[2 * P + 1];               \
    float l0 = (float)(AL)[2 * P], l1 = (float)(AL)[2 * P + 1];               \
    nhh = fmaf(h0, h0, fmaf(h1, h1, nhh));                                    \
    nhl = fmaf(h0, l0, fmaf(h1, l1, nhl));                                    \
  }
#endif

// ============ K5: logits — full-K staging, register-masked MFMA ============
// Staging: pure load->hi/lo->LDS (no shuffles, no masking). Mask is applied
// to A-frags in registers (exact for 0/1). ex comes from 3 extra MFMAs per
// ks on the wave's own tile vs precomputed q_out frags; norm^2 from dot2 on
// the masked frags (h^2+2hl) + 2 shuffles total.
__global__ __launch_bounds__(256, 3) void logits_kernel(
    const float* __restrict__ pk, const float* __restrict__ k_new,
    const _Float16* __restrict__ Sfhi, const _Float16* __restrict__ Sflo,
    const _Float16* __restrict__ qsfT, const _Float16* __restrict__ qofh,
    const _Float16* __restrict__ qofl, const _Float16* __restrict__ maskh,
    const float* __restrict__ amask, float* __restrict__ logits)
{
  __shared__ union {
    struct { _Float16 hi[TB * KSTR]; _Float16 lo[TB * KSTR]; } k;  // 34816 B
    _Float16 ssg[TB * SSTR];                                       // 35328 B
  } u;
  __shared__ float norm2[TB];

  int bk = blockIdx.x / NT2;
  int tile = blockIdx.x % NT2;
  int b = bk >> 3;
  int t0 = tile * TB;
  int tid = threadIdx.x;
  int l15 = tid & 15;
  int q   = (tid >> 4) & 3;
  int w   = tid >> 6;
  int mb  = w * 64;
  int d4  = (tid & 31) * 4;
  int tsub = tid >> 5;
  int lane = tid & 63;

  // ---- staging: burst loads, OOB zero, hi/lo cvt, LDS write. no shuffles ----
  float4 kvr[8];
  #pragma unroll
  for (int iter = 0; iter < 8; ++iter) {
    int tg = t0 + iter * 8 + tsub;
    const float* row = (tg < TP) ? pk + ((size_t)bk * TP + tg) * DD
                                 : k_new + (size_t)bk * DD;   // cndmask, no branch
    kvr[iter] = *(const float4*)(row + d4);
  }
  #pragma unroll
  for (int iter = 0; iter < 8; ++iter) {
    int tl = iter * 8 + tsub;
    int tg = t0 + tl;
    float inb = (tg <= TP) ? 1.f : 0.f;
    float v[4] = {kvr[iter].x * inb, kvr[iter].y * inb,
                  kvr[iter].z * inb, kvr[iter].w * inb};
    f16x4 hi4, lo4;
    #pragma unroll
    for (int j = 0; j < 4; ++j) {
      _Float16 h = (_Float16)v[j];
      hi4[j] = h;
      lo4[j] = (_Float16)(v[j] - (float)h);
    }
    *(f16x4*)&u.k.hi[tl * KSTR + d4] = hi4;
    *(f16x4*)&u.k.lo[tl * KSTR + d4] = lo4;
  }
  __syncthreads();

  // ---- MFMA loop ----
  f32x4 acc[4][4];
  #pragma unroll
  for (int ts = 0; ts < 4; ++ts)
    #pragma unroll
    for (int mt = 0; mt < 4; ++mt)
      acc[ts][mt] = (f32x4){0.f, 0.f, 0.f, 0.f};
  f32x4 exa = (f32x4){0.f, 0.f, 0.f, 0.f};
  float nhh = 0.f, nhl = 0.f;

  const f16x8* SH = (const f16x8*)Sfhi;
  const f16x8* SL = (const f16x8*)Sflo;
  const f16x8* QH = (const f16x8*)qofh;
  const f16x8* QL = (const f16x8*)qofl;
  #pragma unroll
  for (int ks = 0; ks < 4; ++ks) {
    f16x8 mA = *(const f16x8*)&maskh[bk * DD + ks * 32 + q * 8];
    f16x8 qh = QH[(size_t)(bk * 4 + ks) * 64 + lane];
    f16x8 ql = QL[(size_t)(bk * 4 + ks) * 64 + lane];
    f16x8 sh[4], sl[4], ah[4], al[4];
    #pragma unroll
    for (int mt = 0; mt < 4; ++mt) {
      sh[mt] = SH[(size_t)(mt * 4 + ks) * 256 + tid];
      sl[mt] = SL[(size_t)(mt * 4 + ks) * 256 + tid];
    }
    #pragma unroll
    for (int ts = 0; ts < 4; ++ts) {
      ah[ts] = *(const f16x8*)&u.k.hi[(ts * 16 + l15) * KSTR + ks * 32 + q * 8];
      al[ts] = *(const f16x8*)&u.k.lo[(ts * 16 + l15) * KSTR + ks * 32 + q * 8];
    }
    // ex on the wave's own tile (unmasked K x q_out), before masking
    #pragma unroll
    for (int ts = 0; ts < 4; ++ts) {
      if (ts == w) {
        exa = __builtin_amdgcn_mfma_f32_16x16x32_f16(ah[ts], qh, exa, 0, 0, 0);
        exa = __builtin_amdgcn_mfma_f32_16x16x32_f16(al[ts], qh, exa, 0, 0, 0);
        exa = __builtin_amdgcn_mfma_f32_16x16x32_f16(ah[ts], ql, exa, 0, 0, 0);
      }
    }
    // mask A-frags in place (exact: mask is 0/1)
    #pragma unroll
    for (int ts = 0; ts < 4; ++ts) {
      ah[ts] = ah[ts] * mA;
      al[ts] = al[ts] * mA;
    }
    // norm^2 partials on the wave's own tile: h*h and h*l pairs
    #pragma unroll
    for (int ts = 0; ts < 4; ++ts) {
      if (ts == w) {
        NRM_STEP(0, ah[ts], al[ts])
        NRM_STEP(1, ah[ts], al[ts])
        NRM_STEP(2, ah[ts], al[ts])
        NRM_STEP(3, ah[ts], al[ts])
      }
    }
    // sign MFMAs (masked K x S, hi/lo triple)
    #pragma unroll
    for (int ts = 0; ts < 4; ++ts)
      #pragma unroll
      for (int mt = 0; mt < 4; ++mt) {
        acc[ts][mt] = __builtin_amdgcn_mfma_f32_16x16x32_f16(ah[ts], sh[mt], acc[ts][mt], 0, 0, 0);
        acc[ts][mt] = __builtin_amdgcn_mfma_f32_16x16x32_f16(al[ts], sh[mt], acc[ts][mt], 0, 0, 0);
        acc[ts][mt] = __builtin_amdgcn_mfma_f32_16x16x32_f16(ah[ts], sl[mt], acc[ts][mt], 0, 0, 0);
      }
  }

  // norm reduce across the 4 q-groups; wave w owns rows [16w, 16w+16)
  float nrm = nhh + 2.f * nhl;
  nrm += __shfl_xor(nrm, 16);
  nrm += __shfl_xor(nrm, 32);
  if (q == 0) norm2[w * 16 + l15] = nrm;
  __syncthreads();   // done reading kt; LDS reused for sign matrix

  // ---- write sign matrix (C-layout -> [t][m] f16) ----
  #pragma unroll
  for (int ts = 0; ts < 4; ++ts)
    #pragma unroll
    for (int mt = 0; mt < 4; ++mt)
      #pragma unroll
      for (int r = 0; r < 4; ++r) {
        int tl = ts * 16 + q * 4 + r;
        int mm = mb + mt * 16 + l15;
        u.ssg[tl * SSTR + mm] = acc[ts][mt][r] >= 0.f ? (_Float16)1.f : (_Float16)-1.f;
      }
  __syncthreads();

  // ---- est = sign @ qs^T via MFMA; wave w handles t in [16w, 16w+16) ----
  f32x4 eacc = (f32x4){0.f, 0.f, 0.f, 0.f};
  const _Float16* qrow = qsfT + ((size_t)bk * 16 + l15) * MM;
  #pragma unroll
  for (int ks = 0; ks < 8; ++ks) {
    f16x8 as = *(const f16x8*)&u.ssg[(16 * w + l15) * SSTR + ks * 32 + q * 8];
    f16x8 bq = *(const f16x8*)&qrow[ks * 32 + q * 8];
    eacc = __builtin_amdgcn_mfma_f32_16x16x32_f16(as, bq, eacc, 0, 0, 0);
  }

  // ---- assemble: lanes l15 < 4 hold est AND ex for g = l15, rows 16w+q*4+r ----
  if (l15 < 4) {
    int g = l15;
    #pragma unroll
    for (int r = 0; r < 4; ++r) {
      int tl = 16 * w + q * 4 + r;
      int tg = t0 + tl;
      if (tg < TT) {
        float logit = fmaf(eacc[r] * CJL, sqrtf(norm2[tl]), exa[r]) * RSQRT_D;
        logit += (1.f - amask[b * TT + tg]) * NEG_HUGE;
        logits[((size_t)(bk * GG + g)) * TT + tg] = logit;
      }
    }
  }
}

// ============ K6: per-row softmax stats (mx, 1/sum) + zero attn_o ============
__global__ __launch_bounds__(256) void rowstat_kernel(
    const float* __restrict__ logits, float* __restrict__ stats,
    float* __restrict__ attn_o)
{
  int row = blockIdx.x;
  const float* L = logits + (size_t)row * TT;
  int tid = threadIdx.x;
  int lane = tid & 63, wid = tid >> 6;
  __shared__ float red[8];
  if (tid < 128) attn_o[(size_t)row * DD + tid] = 0.f;
  float mx = NEG_HUGE;
  for (int i = tid; i < TT; i += 256) mx = fmaxf(mx, L[i]);
  #pragma unroll
  for (int off = 32; off > 0; off >>= 1) mx = fmaxf(mx, __shfl_xor(mx, off));
  if (lane == 0) red[wid] = mx;
  __syncthreads();
  if (tid == 0) red[4] = fmaxf(fmaxf(red[0], red[1]), fmaxf(red[2], red[3]));
  __syncthreads();
  mx = red[4];
  float sum = 0.f;
  for (int i = tid; i < TT; i += 256) sum += __expf(L[i] - mx);
  #pragma unroll
  for (int off = 32; off > 0; off >>= 1) sum += __shfl_xor(sum, off);
  if (lane == 0) red[wid] = sum;
  __syncthreads();
  if (tid == 0) {
    float s = (red[0] + red[1]) + (red[2] + red[3]);
    stats[row * 2]     = mx;
    stats[row * 2 + 1] = 1.f / s;
  }
}

// ============ K7: out_head = softmax(logits) @ V, exp fused into staging ======
__global__ __launch_bounds__(256) void wv_kernel(
    const float* __restrict__ pv, const float* __restrict__ v_new,
    const float* __restrict__ logits, const float* __restrict__ stats,
    float* __restrict__ attn_out)
{
  __shared__ float wl[GG * TCH];     // 4 KB
  __shared__ float red[8][GG][DD];   // 16 KB
  int bk = blockIdx.x / WCH;
  int chunk = blockIdx.x % WCH;
  int b = bk >> 3, kv = bk & 7;
  int t0 = chunk * TCH;
  const float* wbase = logits + (size_t)bk * GG * TT;
  for (int i = threadIdx.x; i < GG * TCH; i += 256) {
    int g = i >> 8, tloc = i & (TCH - 1);
    int t = t0 + tloc;
    float mxg  = stats[(bk * GG + g) * 2];
    float invg = stats[(bk * GG + g) * 2 + 1];
    wl[i] = (t < TT) ? __expf(wbase[g * TT + t] - mxg) * invg : 0.f;
  }
  __syncthreads();
  int tsub = threadIdx.x >> 5;
  int d4 = (threadIdx.x & 31) * 4;
  int tend = (t0 + TCH < TT) ? t0 + TCH : TT;
  float4 acc[GG];
  #pragma unroll
  for (int g = 0; g < GG; ++g) acc[g] = make_float4(0.f, 0.f, 0.f, 0.f);
  for (int t = t0 + tsub; t < tend; t += 8) {
    float4 v = (t < TP) ? *(const float4*)(pv + ((size_t)bk * TP + t) * DD + d4)
                        : *(const float4*)(v_new + (size_t)bk * DD + d4);
    #pragma unroll
    for (int g = 0; g < GG; ++g) {
      float wv = wl[g * TCH + (t - t0)];   // broadcast
      acc[g].x = fmaf(wv, v.x, acc[g].x);
      acc[g].y = fmaf(wv, v.y, acc[g].y);
      acc[g].z = fmaf(wv, v.z, acc[g].z);
      acc[g].w = fmaf(wv, v.w, acc[g].w);
    }
  }
  #pragma unroll
  for (int g = 0; g < GG; ++g) *(float4*)&red[tsub][g][d4] = acc[g];
  __syncthreads();
  if (threadIdx.x < DD) {
    int d = threadIdx.x;
    #pragma unroll
    for (int g = 0; g < GG; ++g) {
      float s = 0.f;
      #pragma unroll
      for (int ts = 0; ts < 8; ++ts) s += red[ts][g][d];
      atomicAdd(&attn_out[((size_t)b * HH + kv * GG + g) * DD + d], s);
    }
  }
}

// ============ K8: out = attn_out @ Wo^T, Wo read once (all 4 b) ============
__global__ __launch_bounds__(256) void outproj_kernel(
    const float* __restrict__ attn_out, const float* __restrict__ Wo,
    float* __restrict__ out)
{
  __shared__ float al[BB][16][260];   // 66560 B, pad breaks stride-256 conflicts
  int seg = blockIdx.x;
  int tid = threadIdx.x;
  for (int i = tid; i < BB * EE; i += 256) {
    int b = i >> 12, col = i & 4095;
    al[b][col >> 8][col & 255] = attn_out[(size_t)b * EE + col];
  }
  __syncthreads();
  int rloc = tid >> 4, sub = tid & 15;
  int e = seg * 16 + rloc;
  const float* wr = Wo + (size_t)e * EE + sub * 256;
  float acc[BB] = {0.f, 0.f, 0.f, 0.f};
  for (int j = 0; j < 256; j += 4) {
    float4 w4 = *(const float4*)(wr + j);
    #pragma unroll
    for (int b = 0; b < BB; ++b) {
      float4 a4 = *(const float4*)&al[b][sub][j];
      acc[b] = fmaf(w4.x, a4.x, acc[b]);
      acc[b] = fmaf(w4.y, a4.y, acc[b]);
      acc[b] = fmaf(w4.z, a4.z, acc[b]);
      acc[b] = fmaf(w4.w, a4.w, acc[b]);
    }
  }
  #pragma unroll
  for (int b = 0; b < BB; ++b) {
    acc[b] += __shfl_xor(acc[b], 1);
    acc[b] += __shfl_xor(acc[b], 2);
    acc[b] += __shfl_xor(acc[b], 4);
    acc[b] += __shfl_xor(acc[b], 8);
  }
  if (sub == 0) {
    #pragma unroll
    for (int b = 0; b < BB; ++b)
      out[(size_t)b * EE + e] = acc[b];
  }
}

// ===================== launcher =====================
extern "C" void kernel_launch(void* const* d_in, const int* in_sizes, int n_in,
                              void* d_out, int out_size, void* d_ws, size_t ws_size,
                              hipStream_t stream)
{
  const float* hs    = (const float*)d_in[0];
  const float* cosb  = (const float*)d_in[1];
  const float* sinb  = (const float*)d_in[2];
  const float* pk    = (const float*)d_in[3];
  const float* pv    = (const float*)d_in[4];
  const float* amask = (const float*)d_in[5];
  const float* Wq    = (const float*)d_in[6];
  const float* Wk    = (const float*)d_in[7];
  const float* Wv    = (const float*)d_in[8];
  const float* Wo    = (const float*)d_in[9];
  const float* Sp    = (const float*)d_in[10];
  float* out = (float*)d_out;
  float* ws = (float*)d_ws;

  float* q_rope = ws + OFF_Q;
  float* k_new  = ws + OFF_KN;
  float* v_new  = ws + OFF_VN;
  float* maskf  = ws + OFF_MASKF;
  float* stats  = ws + OFF_STATS;
  float* attn_o = ws + OFF_AO;
  _Float16* maskh = (_Float16*)(ws + OFF_MASKH);
  _Float16* qsfT = (_Float16*)(ws + OFF_QSF);
  _Float16* Sfhi = (_Float16*)(ws + OFF_SFRAG);
  _Float16* Sflo = Sfhi + 65536;
  _Float16* qofh = (_Float16*)(ws + OFF_QOFH);
  _Float16* qofl = (_Float16*)(ws + OFF_QOFL);
  float* qkvp   = ws + OFF_QKVP;
  float* scorep = ws + OFF_SCOREP;
  float* logits = ws + OFF_LOGITS;

  int k1_grid = QKV_BLKS + SCORE_BLKS + 16;   // 2448
  k1_kernel<<<k1_grid, 256, 0, stream>>>(hs, pk, Wq, Wk, Wv, Sp,
                                         qkvp, scorep, Sfhi, Sflo);
  qkv_finalize_kernel<<<96, 256, 0, stream>>>(qkvp, cosb, sinb,
                                              q_rope, k_new, v_new);
  topk_kernel<<<BB * HKV, 128, 0, stream>>>(scorep, k_new, maskf, maskh);
  qs_kernel<<<BB * HKV * GG, 256, 0, stream>>>(q_rope, maskf, Sp, qsfT,
                                               qofh, qofl);
  logits_kernel<<<BB * HKV * NT2, 256, 0, stream>>>(pk, k_new, Sfhi, Sflo, qsfT,
                                                    qofh, qofl, maskh, amask,
                                                    logits);
  rowstat_kernel<<<BB * HKV * GG, 256, 0, stream>>>(logits, stats, attn_o);
  wv_kernel<<<BB * HKV * WCH, 256, 0, stream>>>(pv, v_new, logits, stats, attn_o);
  outproj_kernel<<<256, 256, 0, stream>>>(attn_o, Wo, out);
}